// Round 4
// baseline (161.850 us; speedup 1.0000x reference)
//
#include <hip/hip_runtime.h>
#include <hip/hip_bf16.h>
#include <cmath>

typedef __bf16 bf16;
typedef __attribute__((ext_vector_type(8))) __bf16 bf16x8;
typedef __attribute__((ext_vector_type(4))) __bf16 bf16x4;
typedef __attribute__((ext_vector_type(4))) float f32x4;
typedef __attribute__((ext_vector_type(4))) unsigned int u32x4;

#define LD_B 2
#define LD_L 2048
#define LD_D 512
#define N_HEAD 8
#define HD 64
#define NTOK (LD_B * LD_L)  // 4096
#define QKV_LD 1536         // fused QKV row stride

__device__ __forceinline__ void gload16(const void* g, void* l) {
  __builtin_amdgcn_global_load_lds(
      (const __attribute__((address_space(1))) void*)g,
      (__attribute__((address_space(3))) void*)l, 16, 0, 0);
}

// ---------------- cast fp32 -> bf16 for the 6 weight matrices ----------------
__global__ __launch_bounds__(256) void cast6_kernel(
    const float* __restrict__ s0, const float* __restrict__ s1,
    const float* __restrict__ s2, const float* __restrict__ s3,
    const float* __restrict__ s4, const float* __restrict__ s5,
    bf16* __restrict__ d0, bf16* __restrict__ d1, bf16* __restrict__ d2,
    bf16* __restrict__ d3, bf16* __restrict__ d4, bf16* __restrict__ d5)
{
  int idx = blockIdx.x * 256 + threadIdx.x;  // 0..524287
  const float* src; bf16* dst; int off;
  if (idx < 262144) {
    int seg = idx >> 16; off = idx & 65535;
    src = seg == 0 ? s0 : seg == 1 ? s1 : seg == 2 ? s2 : s3;
    dst = seg == 0 ? d0 : seg == 1 ? d1 : seg == 2 ? d2 : d3;
  } else {
    int t = idx - 262144;
    int seg = t >> 17; off = t & 131071;
    src = seg ? s5 : s4;
    dst = seg ? d5 : d4;
  }
  f32x4 v = ((const f32x4*)src)[off];
  bf16x4 o;
  o[0] = (bf16)v[0]; o[1] = (bf16)v[1]; o[2] = (bf16)v[2]; o[3] = (bf16)v[3];
  ((bf16x4*)dst)[off] = o;
}

// ---------------- layernorm (fp32 in, bf16 out), one wave per 512-row -------
__global__ __launch_bounds__(256) void ln_kernel(
    const float* __restrict__ x, const float* __restrict__ g,
    const float* __restrict__ b, bf16* __restrict__ out)
{
  const int wid = threadIdx.x >> 6, lane = threadIdx.x & 63;
  const int row = blockIdx.x * 4 + wid;
  const f32x4* xr = (const f32x4*)(x + (size_t)row * LD_D);
  f32x4 v0 = xr[lane * 2], v1 = xr[lane * 2 + 1];
  float s = v0[0] + v0[1] + v0[2] + v0[3] + v1[0] + v1[1] + v1[2] + v1[3];
#pragma unroll
  for (int off = 32; off; off >>= 1) s += __shfl_xor(s, off);
  const float mu = s * (1.f / 512.f);
  float vs = 0.f;
#pragma unroll
  for (int i = 0; i < 4; ++i) {
    float a0 = v0[i] - mu; vs += a0 * a0;
    float a1 = v1[i] - mu; vs += a1 * a1;
  }
#pragma unroll
  for (int off = 32; off; off >>= 1) vs += __shfl_xor(vs, off);
  const float rstd = rsqrtf(vs * (1.f / 512.f) + 1e-5f);
  const f32x4* gr = (const f32x4*)g;
  const f32x4* br = (const f32x4*)b;
  f32x4 g0 = gr[lane * 2], g1 = gr[lane * 2 + 1];
  f32x4 b0 = br[lane * 2], b1 = br[lane * 2 + 1];
  bf16x8 o;
#pragma unroll
  for (int i = 0; i < 4; ++i) o[i] = (bf16)((v0[i] - mu) * rstd * g0[i] + b0[i]);
#pragma unroll
  for (int i = 0; i < 4; ++i) o[i + 4] = (bf16)((v1[i] - mu) * rstd * g1[i] + b1[i]);
  *(bf16x8*)(&out[(size_t)row * LD_D + lane * 8]) = o;
}

// ---------------- GEMM: C[M,N] = A[M,K] * Bw[N,K]^T, bf16 in, fp32 acc ------
// Tile BM x BN (template), BK=64. 256 thr, 4 waves (2x2), wave tile
// (BM/2)x(BN/2) via FM x FN 16x16x32 frags. global_load_lds(16B) staging,
// double-buffered, 1 barrier/step. LDS linear [rows][64] bf16 with XOR
// swizzle byte^=(row&7)<<4 applied on global SOURCE + ds_read (rule #21).
// EPI: 0 = store bf16; 1 = +res, store f32; 2 = +bias, gelu, store bf16;
//      3 = +bias +res, store f32
template <int BM, int BN, int EPI>
__global__ __launch_bounds__(256) void gemm_kernel(
    const bf16* __restrict__ A, const bf16* __restrict__ Bw,
    int M, int N, int K, bf16* __restrict__ Cb, float* __restrict__ Cf,
    const float* __restrict__ bias, const float* __restrict__ res)
{
  constexpr int WM = BM / 2, WN = BN / 2;
  constexpr int FM = WM / 16, FN = WN / 16;
  constexpr int IA = BM / 32, IB = BN / 32;  // staging chunks/thread
  __shared__ bf16 As[2][BM * 64];
  __shared__ bf16 Bs[2][BN * 64];
  const int tid = threadIdx.x;
  const int lane = tid & 63, wid = tid >> 6;
  const int wm = wid >> 1, wn = wid & 1;
  const int l15 = lane & 15, kg = lane >> 4;
  const int row0 = blockIdx.x * BM, col0 = blockIdx.y * BN;

  // chunk c covers linear LDS bytes [c*16, c*16+16); row = c>>3 (128B rows),
  // 16B-block b = c&7; source col block = b ^ (row&7)  (inverse swizzle).
  int srowA[IA], scolA[IA];
#pragma unroll
  for (int i = 0; i < IA; ++i) {
    int c = i * 256 + tid;
    srowA[i] = c >> 3;
    scolA[i] = ((c & 7) ^ (srowA[i] & 7)) * 8;
  }
  int srowB[IB], scolB[IB];
#pragma unroll
  for (int i = 0; i < IB; ++i) {
    int c = i * 256 + tid;
    srowB[i] = c >> 3;
    scolB[i] = ((c & 7) ^ (srowB[i] & 7)) * 8;
  }

  f32x4 acc[FM][FN];
#pragma unroll
  for (int m = 0; m < FM; ++m)
#pragma unroll
    for (int n = 0; n < FN; ++n) acc[m][n] = (f32x4){0.f, 0.f, 0.f, 0.f};

  const int nt = K >> 6;
  auto STAGE = [&](int buf, int k0) {
#pragma unroll
    for (int i = 0; i < IA; ++i) {
      const bf16* ga = A + (size_t)(row0 + srowA[i]) * K + k0 + scolA[i];
      char* la = (char*)&As[buf][0] + i * 4096 + wid * 1024;
      gload16(ga, la);
    }
#pragma unroll
    for (int i = 0; i < IB; ++i) {
      const bf16* gb = Bw + (size_t)(col0 + srowB[i]) * K + k0 + scolB[i];
      char* lb = (char*)&Bs[buf][0] + i * 4096 + wid * 1024;
      gload16(gb, lb);
    }
  };

  STAGE(0, 0);
  __syncthreads();
  for (int t = 0; t < nt; ++t) {
    if (t + 1 < nt) STAGE((t + 1) & 1, (t + 1) << 6);
    const char* pa = (const char*)&As[t & 1][0];
    const char* pb = (const char*)&Bs[t & 1][0];
#pragma unroll
    for (int kk = 0; kk < 2; ++kk) {
      bf16x8 af[FM], bf[FN];
#pragma unroll
      for (int m = 0; m < FM; ++m) {
        const int r = wm * WM + m * 16 + l15;
        int off = r * 128 + kk * 64 + kg * 16;
        off ^= (r & 7) << 4;
        af[m] = *(const bf16x8*)(pa + off);
      }
#pragma unroll
      for (int n = 0; n < FN; ++n) {
        const int r = wn * WN + n * 16 + l15;
        int off = r * 128 + kk * 64 + kg * 16;
        off ^= (r & 7) << 4;
        bf[n] = *(const bf16x8*)(pb + off);
      }
#pragma unroll
      for (int m = 0; m < FM; ++m)
#pragma unroll
        for (int n = 0; n < FN; ++n)
          acc[m][n] = __builtin_amdgcn_mfma_f32_16x16x32_bf16(af[m], bf[n], acc[m][n], 0, 0, 0);
    }
    __syncthreads();
  }

  const int orow = row0 + wm * WM, ocol = col0 + wn * WN;
#pragma unroll
  for (int m = 0; m < FM; ++m) {
#pragma unroll
    for (int n = 0; n < FN; ++n) {
#pragma unroll
      for (int e = 0; e < 4; ++e) {
        const int rr = orow + m * 16 + kg * 4 + e;   // C/D: row=(lane>>4)*4+reg
        const int cc = ocol + n * 16 + l15;          //      col=lane&15
        const float v = acc[m][n][e];
        const size_t oi = (size_t)rr * N + cc;
        if constexpr (EPI == 0) {
          Cb[oi] = (bf16)v;
        } else if constexpr (EPI == 1) {
          Cf[oi] = v + res[oi];
        } else if constexpr (EPI == 2) {
          float t2 = v + bias[cc];
          Cb[oi] = (bf16)(0.5f * t2 * (1.f + erff(t2 * 0.70710678118654752f)));
        } else {
          Cf[oi] = v + bias[cc] + res[oi];
        }
      }
    }
  }
}

// ---------------- sliding-window causal attention, MFMA version -------------
// Input: fused QKV buffer [4096][1536] (Q cols 0-511, K 512-1023, V 1024-1535).
// Block = 64 queries of one (b,h). Keys j = q0-63+k for LDS k=0..127.
// Wave w computes queries w*16..w*16+15. S[16][128] = Q.K^T via 16 MFMA;
// masked softmax in-register (band: k in [qi, qi+63], qi = wid*16+kg*4+e,
// plus k >= 63-q0 for the first tile); P via per-wave LDS; O = P.V (V^T LDS).
__global__ __launch_bounds__(256) void attn_kernel(
    const bf16* __restrict__ QKV, bf16* __restrict__ Og)
{
  constexpr int STK = 72;   // 144B rows -> 2-way banks on frag reads
  constexpr int STP = 136;  // 272B rows -> 2-way banks
  __shared__ bf16 Ks[128][STK];
  __shared__ bf16 Qs[64][STK];
  __shared__ bf16 Vt[64][STP];      // Vt[d][k]
  __shared__ bf16 Ps[4][16][STP];   // per-wave P
  const int tid = threadIdx.x;
  const int qt = blockIdx.x, bh = blockIdx.y;
  const int b = bh >> 3, h = bh & 7;
  const int q0 = qt * 64;
  const int j0 = q0 - 63;
  const size_t baseQ = (size_t)b * LD_L * QKV_LD + h * HD;
  const size_t baseK = baseQ + 512;
  const size_t baseV = baseQ + 1024;
  const size_t baseO = (size_t)b * LD_L * LD_D + h * HD;

  // stage K rows 0..127 and V transposed (zero-fill out-of-range rows)
  for (int c = tid; c < 128 * 8; c += 256) {
    const int r = c >> 3, d0 = (c & 7) * 8;
    const int j = j0 + r;
    u32x4 kv = (u32x4){0u, 0u, 0u, 0u};
    bf16x8 vv = (bf16x8)(__bf16)0.f;
    if (j >= 0 && j < LD_L) {
      kv = *(const u32x4*)(QKV + baseK + (size_t)j * QKV_LD + d0);
      vv = *(const bf16x8*)(QKV + baseV + (size_t)j * QKV_LD + d0);
    }
    *(u32x4*)(&Ks[r][d0]) = kv;
#pragma unroll
    for (int dd = 0; dd < 8; ++dd) Vt[d0 + dd][r] = vv[dd];
  }
  for (int c = tid; c < 64 * 8; c += 256) {
    const int r = c >> 3, d0 = (c & 7) * 8;
    *(u32x4*)(&Qs[r][d0]) =
        *(const u32x4*)(QKV + baseQ + (size_t)(q0 + r) * QKV_LD + d0);
  }
  __syncthreads();

  const int lane = tid & 63, wid = tid >> 6;
  const int l15 = lane & 15, kg = lane >> 4;
  const int klo = 63 - q0;  // j>=0 constraint (only binds for first tile)

  // ---- S = Q K^T ----
  bf16x8 qf[2];
#pragma unroll
  for (int kk = 0; kk < 2; ++kk)
    qf[kk] = *(const bf16x8*)(&Qs[wid * 16 + l15][kk * 32 + kg * 8]);
  f32x4 s[8];
#pragma unroll
  for (int n = 0; n < 8; ++n) s[n] = (f32x4){0.f, 0.f, 0.f, 0.f};
#pragma unroll
  for (int kk = 0; kk < 2; ++kk)
#pragma unroll
    for (int n = 0; n < 8; ++n) {
      bf16x8 kf = *(const bf16x8*)(&Ks[n * 16 + l15][kk * 32 + kg * 8]);
      s[n] = __builtin_amdgcn_mfma_f32_16x16x32_bf16(qf[kk], kf, s[n], 0, 0, 0);
    }

  // ---- masked softmax over k (each lane: 4 rows x 8 cols) ----
  float p[8][4];
  float mx[4], sm[4];
#pragma unroll
  for (int e = 0; e < 4; ++e) { mx[e] = -INFINITY; sm[e] = 0.f; }
#pragma unroll
  for (int n = 0; n < 8; ++n) {
    const int k = n * 16 + l15;
#pragma unroll
    for (int e = 0; e < 4; ++e) {
      const int qi = wid * 16 + kg * 4 + e;  // query row within the 64-tile
      const bool ok = (k >= qi) & (k <= qi + 63) & (k >= klo);
      float sv = ok ? s[n][e] * 0.125f : -INFINITY;
      p[n][e] = sv;
      mx[e] = fmaxf(mx[e], sv);
    }
  }
#pragma unroll
  for (int off = 8; off; off >>= 1)
#pragma unroll
    for (int e = 0; e < 4; ++e) mx[e] = fmaxf(mx[e], __shfl_xor(mx[e], off));
#pragma unroll
  for (int n = 0; n < 8; ++n)
#pragma unroll
    for (int e = 0; e < 4; ++e) {
      float pv = (p[n][e] == -INFINITY) ? 0.f : __expf(p[n][e] - mx[e]);
      p[n][e] = pv;
      sm[e] += pv;
    }
#pragma unroll
  for (int off = 8; off; off >>= 1)
#pragma unroll
    for (int e = 0; e < 4; ++e) sm[e] += __shfl_xor(sm[e], off);
  float rs[4];
#pragma unroll
  for (int e = 0; e < 4; ++e) rs[e] = 1.f / sm[e];

  // ---- P -> LDS (A-frag layout for PV) ----
#pragma unroll
  for (int n = 0; n < 8; ++n)
#pragma unroll
    for (int e = 0; e < 4; ++e)
      Ps[wid][kg * 4 + e][n * 16 + l15] = (bf16)(p[n][e] * rs[e]);

  // ---- O = P V ----  (per-wave Ps; compiler orders the DS write->read)
  f32x4 o[4];
#pragma unroll
  for (int n = 0; n < 4; ++n) o[n] = (f32x4){0.f, 0.f, 0.f, 0.f};
#pragma unroll
  for (int ks = 0; ks < 4; ++ks) {
    bf16x8 pf = *(const bf16x8*)(&Ps[wid][l15][ks * 32 + kg * 8]);
#pragma unroll
    for (int n = 0; n < 4; ++n) {
      bf16x8 vf = *(const bf16x8*)(&Vt[n * 16 + l15][ks * 32 + kg * 8]);
      o[n] = __builtin_amdgcn_mfma_f32_16x16x32_bf16(pf, vf, o[n], 0, 0, 0);
    }
  }

  const int q = q0 + wid * 16 + kg * 4;
#pragma unroll
  for (int n = 0; n < 4; ++n)
#pragma unroll
    for (int e = 0; e < 4; ++e)
      Og[baseO + (size_t)(q + e) * LD_D + n * 16 + l15] = (bf16)o[n][e];
}

// ---------------- launch ----------------
extern "C" void kernel_launch(void* const* d_in, const int* in_sizes, int n_in,
                              void* d_out, int out_size, void* d_ws, size_t ws_size,
                              hipStream_t stream)
{
  const float* query = (const float*)d_in[0];
  const float* ln_g = (const float*)d_in[1];
  const float* ln_b = (const float*)d_in[2];
  const float* wq = (const float*)d_in[3];
  const float* wk = (const float*)d_in[4];
  const float* wv = (const float*)d_in[5];
  const float* wo = (const float*)d_in[6];
  const float* w1 = (const float*)d_in[7];
  const float* b1 = (const float*)d_in[8];
  const float* w2 = (const float*)d_in[9];
  const float* b2 = (const float*)d_in[10];
  float* out = (float*)d_out;

  char* ws = (char*)d_ws;
  bf16* WQKVb = (bf16*)(ws + 0x000000);  // [1536][512] = 1.5MB
  bf16* WOb = (bf16*)(ws + 0x180000);    // 512KB
  bf16* W1b = (bf16*)(ws + 0x200000);    // 1MB
  bf16* W2b = (bf16*)(ws + 0x300000);    // 1MB
  bf16* XLN = (bf16*)(ws + 0x400000);    // 4MB
  bf16* QKVb = (bf16*)(ws + 0x800000);   // [4096][1536] = 12MB
  bf16* ATb = (bf16*)(ws + 0x1400000);   // 4MB
  float* Q2 = (float*)(ws + 0x1800000);  // 8MB
  bf16* YLN = (bf16*)(ws + 0x2000000);   // 4MB
  bf16* Hb = (bf16*)(ws + 0x2400000);    // 8MB (end 44MB)

  cast6_kernel<<<2048, 256, 0, stream>>>(
      wq, wk, wv, wo, w1, w2,
      WQKVb, WQKVb + 262144, WQKVb + 524288, WOb, W1b, W2b);
  ln_kernel<<<1024, 256, 0, stream>>>(query, ln_g, ln_b, XLN);
  gemm_kernel<128, 128, 0><<<dim3(32, 12), 256, 0, stream>>>(
      XLN, WQKVb, NTOK, QKV_LD, 512, QKVb, nullptr, nullptr, nullptr);
  attn_kernel<<<dim3(32, 16), 256, 0, stream>>>(QKVb, ATb);
  gemm_kernel<128, 64, 1><<<dim3(32, 8), 256, 0, stream>>>(
      ATb, WOb, NTOK, 512, 512, nullptr, Q2, nullptr, query);
  ln_kernel<<<1024, 256, 0, stream>>>(Q2, ln_g, ln_b, YLN);
  gemm_kernel<128, 128, 2><<<dim3(32, 8), 256, 0, stream>>>(
      YLN, W1b, NTOK, 1024, 512, Hb, nullptr, b1, nullptr);
  gemm_kernel<128, 64, 3><<<dim3(32, 8), 256, 0, stream>>>(
      Hb, W2b, NTOK, 512, 1024, nullptr, out, b2, Q2);
}

// Round 5
// 149.823 us; speedup vs baseline: 1.0803x; 1.0803x over previous
//
#include <hip/hip_runtime.h>
#include <hip/hip_bf16.h>
#include <cmath>

typedef __bf16 bf16;
typedef __attribute__((ext_vector_type(8))) __bf16 bf16x8;
typedef __attribute__((ext_vector_type(4))) __bf16 bf16x4;
typedef __attribute__((ext_vector_type(4))) float f32x4;
typedef __attribute__((ext_vector_type(4))) unsigned int u32x4;

#define LD_B 2
#define LD_L 2048
#define LD_D 512
#define N_HEAD 8
#define HD 64
#define NTOK (LD_B * LD_L)  // 4096
#define QKV_LD 1536         // fused QKV row stride

__device__ __forceinline__ void gload16(const void* g, void* l) {
  __builtin_amdgcn_global_load_lds(
      (const __attribute__((address_space(1))) void*)g,
      (__attribute__((address_space(3))) void*)l, 16, 0, 0);
}

// ------------- prep: LN1 (blocks 0..1023) + weight cast (blocks 1024..3071) --
__global__ __launch_bounds__(256) void prep_kernel(
    const float* __restrict__ x, const float* __restrict__ g,
    const float* __restrict__ b, bf16* __restrict__ xln,
    const float* __restrict__ s0, const float* __restrict__ s1,
    const float* __restrict__ s2, const float* __restrict__ s3,
    const float* __restrict__ s4, const float* __restrict__ s5,
    bf16* __restrict__ d0, bf16* __restrict__ d1, bf16* __restrict__ d2,
    bf16* __restrict__ d3, bf16* __restrict__ d4, bf16* __restrict__ d5)
{
  if (blockIdx.x >= 1024) {
    int idx = (blockIdx.x - 1024) * 256 + threadIdx.x;  // 0..524287
    const float* src; bf16* dst; int off;
    if (idx < 262144) {
      int seg = idx >> 16; off = idx & 65535;
      src = seg == 0 ? s0 : seg == 1 ? s1 : seg == 2 ? s2 : s3;
      dst = seg == 0 ? d0 : seg == 1 ? d1 : seg == 2 ? d2 : d3;
    } else {
      int t = idx - 262144;
      int seg = t >> 17; off = t & 131071;
      src = seg ? s5 : s4;
      dst = seg ? d5 : d4;
    }
    f32x4 v = ((const f32x4*)src)[off];
    bf16x4 o;
    o[0] = (bf16)v[0]; o[1] = (bf16)v[1]; o[2] = (bf16)v[2]; o[3] = (bf16)v[3];
    ((bf16x4*)dst)[off] = o;
    return;
  }
  const int wid = threadIdx.x >> 6, lane = threadIdx.x & 63;
  const int row = blockIdx.x * 4 + wid;
  const f32x4* xr = (const f32x4*)(x + (size_t)row * LD_D);
  f32x4 v0 = xr[lane * 2], v1 = xr[lane * 2 + 1];
  float s = v0[0] + v0[1] + v0[2] + v0[3] + v1[0] + v1[1] + v1[2] + v1[3];
#pragma unroll
  for (int off = 32; off; off >>= 1) s += __shfl_xor(s, off);
  const float mu = s * (1.f / 512.f);
  float vs = 0.f;
#pragma unroll
  for (int i = 0; i < 4; ++i) {
    float a0 = v0[i] - mu; vs += a0 * a0;
    float a1 = v1[i] - mu; vs += a1 * a1;
  }
#pragma unroll
  for (int off = 32; off; off >>= 1) vs += __shfl_xor(vs, off);
  const float rstd = rsqrtf(vs * (1.f / 512.f) + 1e-5f);
  const f32x4* gr = (const f32x4*)g;
  const f32x4* br = (const f32x4*)b;
  f32x4 g0 = gr[lane * 2], g1 = gr[lane * 2 + 1];
  f32x4 b0 = br[lane * 2], b1 = br[lane * 2 + 1];
  bf16x8 o;
#pragma unroll
  for (int i = 0; i < 4; ++i) o[i] = (bf16)((v0[i] - mu) * rstd * g0[i] + b0[i]);
#pragma unroll
  for (int i = 0; i < 4; ++i) o[i + 4] = (bf16)((v1[i] - mu) * rstd * g1[i] + b1[i]);
  *(bf16x8*)(&xln[(size_t)row * LD_D + lane * 8]) = o;
}

// ---------------- layernorm (fp32 in, bf16 out), one wave per 512-row -------
__global__ __launch_bounds__(256) void ln_kernel(
    const float* __restrict__ x, const float* __restrict__ g,
    const float* __restrict__ b, bf16* __restrict__ out)
{
  const int wid = threadIdx.x >> 6, lane = threadIdx.x & 63;
  const int row = blockIdx.x * 4 + wid;
  const f32x4* xr = (const f32x4*)(x + (size_t)row * LD_D);
  f32x4 v0 = xr[lane * 2], v1 = xr[lane * 2 + 1];
  float s = v0[0] + v0[1] + v0[2] + v0[3] + v1[0] + v1[1] + v1[2] + v1[3];
#pragma unroll
  for (int off = 32; off; off >>= 1) s += __shfl_xor(s, off);
  const float mu = s * (1.f / 512.f);
  float vs = 0.f;
#pragma unroll
  for (int i = 0; i < 4; ++i) {
    float a0 = v0[i] - mu; vs += a0 * a0;
    float a1 = v1[i] - mu; vs += a1 * a1;
  }
#pragma unroll
  for (int off = 32; off; off >>= 1) vs += __shfl_xor(vs, off);
  const float rstd = rsqrtf(vs * (1.f / 512.f) + 1e-5f);
  const f32x4* gr = (const f32x4*)g;
  const f32x4* br = (const f32x4*)b;
  f32x4 g0 = gr[lane * 2], g1 = gr[lane * 2 + 1];
  f32x4 b0 = br[lane * 2], b1 = br[lane * 2 + 1];
  bf16x8 o;
#pragma unroll
  for (int i = 0; i < 4; ++i) o[i] = (bf16)((v0[i] - mu) * rstd * g0[i] + b0[i]);
#pragma unroll
  for (int i = 0; i < 4; ++i) o[i + 4] = (bf16)((v1[i] - mu) * rstd * g1[i] + b1[i]);
  *(bf16x8*)(&out[(size_t)row * LD_D + lane * 8]) = o;
}

// ---------------- GEMM: C[M,N] = A[M,K] * Bw[N,K]^T, bf16 in, fp32 acc ------
// BM=BN=64, BK=64 (empirically best: 32KB LDS -> 4-5 blocks/CU). 256 thr,
// 4 waves (2x2), wave 32x32 via 2x2 16x16x32 frags. global_load_lds(16B)
// staging, double-buffered, 1 barrier/step. LDS linear [64][64] bf16 with
// XOR swizzle byte^=(row&7)<<4 on global SOURCE + ds_read (rule #21).
// EPI: 0 = store bf16; 1 = +res, store f32; 2 = +bias, gelu, store bf16;
//      3 = +bias +res, store f32
template <int EPI>
__global__ __launch_bounds__(256) void gemm_kernel(
    const bf16* __restrict__ A, const bf16* __restrict__ Bw,
    int M, int N, int K, bf16* __restrict__ Cb, float* __restrict__ Cf,
    const float* __restrict__ bias, const float* __restrict__ res)
{
  __shared__ bf16 As[2][4096];
  __shared__ bf16 Bs[2][4096];
  const int tid = threadIdx.x;
  const int lane = tid & 63, wid = tid >> 6;
  const int wm = wid >> 1, wn = wid & 1;
  const int l15 = lane & 15, kg = lane >> 4;
  const int row0 = blockIdx.x * 64, col0 = blockIdx.y * 64;

  // chunk c covers linear LDS bytes [c*16, c*16+16); row = c>>3 (128B rows),
  // 16B-block b = c&7; source col block = b ^ (row&7)  (inverse swizzle).
  int srow[2], scol[2];
#pragma unroll
  for (int i = 0; i < 2; ++i) {
    int c = i * 256 + tid;
    srow[i] = c >> 3;
    scol[i] = ((c & 7) ^ (srow[i] & 7)) * 8;
  }

  f32x4 acc[2][2];
#pragma unroll
  for (int m = 0; m < 2; ++m)
#pragma unroll
    for (int n = 0; n < 2; ++n) acc[m][n] = (f32x4){0.f, 0.f, 0.f, 0.f};

  const int nt = K >> 6;
#define STAGE(buf, k0)                                                      \
  {                                                                         \
    _Pragma("unroll")                                                       \
    for (int i = 0; i < 2; ++i) {                                           \
      const bf16* ga = A + (size_t)(row0 + srow[i]) * K + (k0) + scol[i];   \
      const bf16* gb = Bw + (size_t)(col0 + srow[i]) * K + (k0) + scol[i];  \
      char* la = (char*)&As[buf][0] + (i * 4 + wid) * 1024;                 \
      char* lb = (char*)&Bs[buf][0] + (i * 4 + wid) * 1024;                 \
      gload16(ga, la);                                                      \
      gload16(gb, lb);                                                      \
    }                                                                       \
  }

  STAGE(0, 0);
  __syncthreads();
  for (int t = 0; t < nt; ++t) {
    if (t + 1 < nt) STAGE((t + 1) & 1, (t + 1) << 6);
    const char* pa = (const char*)&As[t & 1][0];
    const char* pb = (const char*)&Bs[t & 1][0];
#pragma unroll
    for (int kk = 0; kk < 2; ++kk) {
      bf16x8 af[2], bf[2];
#pragma unroll
      for (int m = 0; m < 2; ++m) {
        const int r = wm * 32 + m * 16 + l15;
        int off = r * 128 + kk * 64 + kg * 16;
        off ^= (r & 7) << 4;
        af[m] = *(const bf16x8*)(pa + off);
      }
#pragma unroll
      for (int n = 0; n < 2; ++n) {
        const int r = wn * 32 + n * 16 + l15;
        int off = r * 128 + kk * 64 + kg * 16;
        off ^= (r & 7) << 4;
        bf[n] = *(const bf16x8*)(pb + off);
      }
#pragma unroll
      for (int m = 0; m < 2; ++m)
#pragma unroll
        for (int n = 0; n < 2; ++n)
          acc[m][n] = __builtin_amdgcn_mfma_f32_16x16x32_bf16(af[m], bf[n], acc[m][n], 0, 0, 0);
    }
    __syncthreads();
  }
#undef STAGE

  const int orow = row0 + wm * 32, ocol = col0 + wn * 32;
#pragma unroll
  for (int m = 0; m < 2; ++m) {
#pragma unroll
    for (int n = 0; n < 2; ++n) {
#pragma unroll
      for (int e = 0; e < 4; ++e) {
        const int rr = orow + m * 16 + kg * 4 + e;   // C/D: row=(lane>>4)*4+reg
        const int cc = ocol + n * 16 + l15;          //      col=lane&15
        const float v = acc[m][n][e];
        const size_t oi = (size_t)rr * N + cc;
        if constexpr (EPI == 0) {
          Cb[oi] = (bf16)v;
        } else if constexpr (EPI == 1) {
          Cf[oi] = v + res[oi];
        } else if constexpr (EPI == 2) {
          float t2 = v + bias[cc];
          Cb[oi] = (bf16)(0.5f * t2 * (1.f + erff(t2 * 0.70710678118654752f)));
        } else {
          Cf[oi] = v + bias[cc] + res[oi];
        }
      }
    }
  }
}

// ---------------- sliding-window causal attention, MFMA version -------------
// Input: fused QKV buffer [4096][1536] (Q cols 0-511, K 512-1023, V 1024-1535).
// Block = 64 queries of one (b,h). Keys j = q0-63+k for LDS k=0..127.
// Wave w computes queries w*16..w*16+15. S[16][128] = Q.K^T via 16 MFMA;
// masked softmax in-register (band: k in [qi, qi+63], qi = wid*16+kg*4+e,
// plus k >= 63-q0 for the first tile); P via per-wave LDS; O = P.V (V^T LDS).
__global__ __launch_bounds__(256) void attn_kernel(
    const bf16* __restrict__ QKV, bf16* __restrict__ Og)
{
  constexpr int STK = 72;   // 144B rows -> 2-way banks on frag reads
  constexpr int STP = 136;  // 272B rows -> 2-way banks
  __shared__ bf16 Ks[128][STK];
  __shared__ bf16 Qs[64][STK];
  __shared__ bf16 Vt[64][STP];      // Vt[d][k]
  __shared__ bf16 Ps[4][16][STP];   // per-wave P
  const int tid = threadIdx.x;
  const int qt = blockIdx.x, bh = blockIdx.y;
  const int b = bh >> 3, h = bh & 7;
  const int q0 = qt * 64;
  const int j0 = q0 - 63;
  const size_t baseQ = (size_t)b * LD_L * QKV_LD + h * HD;
  const size_t baseK = baseQ + 512;
  const size_t baseV = baseQ + 1024;
  const size_t baseO = (size_t)b * LD_L * LD_D + h * HD;

  // stage K rows 0..127 and V transposed (zero-fill out-of-range rows)
  for (int c = tid; c < 128 * 8; c += 256) {
    const int r = c >> 3, d0 = (c & 7) * 8;
    const int j = j0 + r;
    u32x4 kv = (u32x4){0u, 0u, 0u, 0u};
    bf16x8 vv = (bf16x8)(__bf16)0.f;
    if (j >= 0 && j < LD_L) {
      kv = *(const u32x4*)(QKV + baseK + (size_t)j * QKV_LD + d0);
      vv = *(const bf16x8*)(QKV + baseV + (size_t)j * QKV_LD + d0);
    }
    *(u32x4*)(&Ks[r][d0]) = kv;
#pragma unroll
    for (int dd = 0; dd < 8; ++dd) Vt[d0 + dd][r] = vv[dd];
  }
  for (int c = tid; c < 64 * 8; c += 256) {
    const int r = c >> 3, d0 = (c & 7) * 8;
    *(u32x4*)(&Qs[r][d0]) =
        *(const u32x4*)(QKV + baseQ + (size_t)(q0 + r) * QKV_LD + d0);
  }
  __syncthreads();

  const int lane = tid & 63, wid = tid >> 6;
  const int l15 = lane & 15, kg = lane >> 4;
  const int klo = 63 - q0;  // j>=0 constraint (only binds for first tile)

  // ---- S = Q K^T ----
  bf16x8 qf[2];
#pragma unroll
  for (int kk = 0; kk < 2; ++kk)
    qf[kk] = *(const bf16x8*)(&Qs[wid * 16 + l15][kk * 32 + kg * 8]);
  f32x4 s[8];
#pragma unroll
  for (int n = 0; n < 8; ++n) s[n] = (f32x4){0.f, 0.f, 0.f, 0.f};
#pragma unroll
  for (int kk = 0; kk < 2; ++kk)
#pragma unroll
    for (int n = 0; n < 8; ++n) {
      bf16x8 kf = *(const bf16x8*)(&Ks[n * 16 + l15][kk * 32 + kg * 8]);
      s[n] = __builtin_amdgcn_mfma_f32_16x16x32_bf16(qf[kk], kf, s[n], 0, 0, 0);
    }

  // ---- masked softmax over k (each lane: 4 rows x 8 cols) ----
  float p[8][4];
  float mx[4], sm[4];
#pragma unroll
  for (int e = 0; e < 4; ++e) { mx[e] = -INFINITY; sm[e] = 0.f; }
#pragma unroll
  for (int n = 0; n < 8; ++n) {
    const int k = n * 16 + l15;
#pragma unroll
    for (int e = 0; e < 4; ++e) {
      const int qi = wid * 16 + kg * 4 + e;  // query row within the 64-tile
      const bool ok = (k >= qi) & (k <= qi + 63) & (k >= klo);
      float sv = ok ? s[n][e] * 0.125f : -INFINITY;
      p[n][e] = sv;
      mx[e] = fmaxf(mx[e], sv);
    }
  }
#pragma unroll
  for (int off = 8; off; off >>= 1)
#pragma unroll
    for (int e = 0; e < 4; ++e) mx[e] = fmaxf(mx[e], __shfl_xor(mx[e], off));
#pragma unroll
  for (int n = 0; n < 8; ++n)
#pragma unroll
    for (int e = 0; e < 4; ++e) {
      float pv = (p[n][e] == -INFINITY) ? 0.f : __expf(p[n][e] - mx[e]);
      p[n][e] = pv;
      sm[e] += pv;
    }
#pragma unroll
  for (int off = 8; off; off >>= 1)
#pragma unroll
    for (int e = 0; e < 4; ++e) sm[e] += __shfl_xor(sm[e], off);
  float rs[4];
#pragma unroll
  for (int e = 0; e < 4; ++e) rs[e] = 1.f / sm[e];

  // ---- P -> LDS (A-frag layout for PV) ----
#pragma unroll
  for (int n = 0; n < 8; ++n)
#pragma unroll
    for (int e = 0; e < 4; ++e)
      Ps[wid][kg * 4 + e][n * 16 + l15] = (bf16)(p[n][e] * rs[e]);

  // ---- O = P V ----  (per-wave Ps; compiler orders the DS write->read)
  f32x4 o[4];
#pragma unroll
  for (int n = 0; n < 4; ++n) o[n] = (f32x4){0.f, 0.f, 0.f, 0.f};
#pragma unroll
  for (int ks = 0; ks < 4; ++ks) {
    bf16x8 pf = *(const bf16x8*)(&Ps[wid][l15][ks * 32 + kg * 8]);
#pragma unroll
    for (int n = 0; n < 4; ++n) {
      bf16x8 vf = *(const bf16x8*)(&Vt[n * 16 + l15][ks * 32 + kg * 8]);
      o[n] = __builtin_amdgcn_mfma_f32_16x16x32_bf16(pf, vf, o[n], 0, 0, 0);
    }
  }

  const int q = q0 + wid * 16 + kg * 4;
#pragma unroll
  for (int n = 0; n < 4; ++n)
#pragma unroll
    for (int e = 0; e < 4; ++e)
      Og[baseO + (size_t)(q + e) * LD_D + n * 16 + l15] = (bf16)o[n][e];
}

// ---------------- launch ----------------
extern "C" void kernel_launch(void* const* d_in, const int* in_sizes, int n_in,
                              void* d_out, int out_size, void* d_ws, size_t ws_size,
                              hipStream_t stream)
{
  const float* query = (const float*)d_in[0];
  const float* ln_g = (const float*)d_in[1];
  const float* ln_b = (const float*)d_in[2];
  const float* wq = (const float*)d_in[3];
  const float* wk = (const float*)d_in[4];
  const float* wv = (const float*)d_in[5];
  const float* wo = (const float*)d_in[6];
  const float* w1 = (const float*)d_in[7];
  const float* b1 = (const float*)d_in[8];
  const float* w2 = (const float*)d_in[9];
  const float* b2 = (const float*)d_in[10];
  float* out = (float*)d_out;

  char* ws = (char*)d_ws;
  bf16* WQKVb = (bf16*)(ws + 0x000000);  // [1536][512] = 1.5MB
  bf16* WOb = (bf16*)(ws + 0x180000);    // 512KB
  bf16* W1b = (bf16*)(ws + 0x200000);    // 1MB
  bf16* W2b = (bf16*)(ws + 0x300000);    // 1MB
  bf16* XLN = (bf16*)(ws + 0x400000);    // 4MB
  bf16* QKVb = (bf16*)(ws + 0x800000);   // [4096][1536] = 12MB
  bf16* ATb = (bf16*)(ws + 0x1400000);   // 4MB
  float* Q2 = (float*)(ws + 0x1800000);  // 8MB
  bf16* YLN = (bf16*)(ws + 0x2000000);   // 4MB
  bf16* Hb = (bf16*)(ws + 0x2400000);    // 8MB (end 44MB)

  prep_kernel<<<3072, 256, 0, stream>>>(
      query, ln_g, ln_b, XLN,
      wq, wk, wv, wo, w1, w2,
      WQKVb, WQKVb + 262144, WQKVb + 524288, WOb, W1b, W2b);
  gemm_kernel<0><<<dim3(64, 24), 256, 0, stream>>>(
      XLN, WQKVb, NTOK, QKV_LD, 512, QKVb, nullptr, nullptr, nullptr);
  attn_kernel<<<dim3(32, 16), 256, 0, stream>>>(QKVb, ATb);
  gemm_kernel<1><<<dim3(64, 8), 256, 0, stream>>>(
      ATb, WOb, NTOK, 512, 512, nullptr, Q2, nullptr, query);
  ln_kernel<<<1024, 256, 0, stream>>>(Q2, ln_g, ln_b, YLN);
  gemm_kernel<2><<<dim3(64, 16), 256, 0, stream>>>(
      YLN, W1b, NTOK, 1024, 512, Hb, nullptr, b1, nullptr);
  gemm_kernel<3><<<dim3(64, 8), 256, 0, stream>>>(
      Hb, W2b, NTOK, 512, 1024, nullptr, out, b2, Q2);
}